// Round 9
// baseline (216.361 us; speedup 1.0000x reference)
//
#include <hip/hip_runtime.h>
#include <hip/hip_fp16.h>

#define D 128
#define BSHIFT 6
#define BSIZE 64         // nodes per bucket
#define NBMAX 1024       // supports N <= 65536
#define BCAP 3072        // slab capacity per bucket (E[cnt]=2046, >20 sigma safe)
#define PA_BLOCKS 256
#define OVF_CAP 65536
#define GB_THREADS 1024  // gatherB block: 16 waves, one bucket per block

using half8 = __attribute__((ext_vector_type(8))) _Float16;
using float4v = __attribute__((ext_vector_type(4))) float;

// ---- A1: per-block LDS histogram of dst>>6; write block-major partials ------
__global__ __launch_bounds__(256) void histA_kernel(const int* __restrict__ dst,
                                                    int* __restrict__ ph, int E, int NB) {
    __shared__ int hist[NBMAX];
    int t = threadIdx.x;
    for (int b = t; b < NB; b += 256) hist[b] = 0;
    __syncthreads();
    int chunk = (E + gridDim.x - 1) / gridDim.x;
    int start = blockIdx.x * chunk;
    int end = min(start + chunk, E);
    for (int i = start + t; i < end; i += 256)
        atomicAdd(&hist[dst[i] >> BSHIFT], 1);
    __syncthreads();
    int* row = ph + (size_t)blockIdx.x * NB;
    for (int b = t; b < NB; b += 256) row[b] = hist[b];
}

// ---- A2: per-bucket exclusive scan over the 256 block partials --------------
__global__ __launch_bounds__(PA_BLOCKS) void scanA_kernel(int* __restrict__ ph,
                                                          int* __restrict__ bucket_cnt,
                                                          int NB) {
    __shared__ int sh[PA_BLOCKS];
    int b = blockIdx.x;
    int t = threadIdx.x;
    int v = ph[(size_t)t * NB + b];
    sh[t] = v;
    __syncthreads();
    for (int off = 1; off < PA_BLOCKS; off <<= 1) {
        int add = (t >= off) ? sh[t - off] : 0;
        __syncthreads();
        sh[t] += add;
        __syncthreads();
    }
    ph[(size_t)t * NB + b] = sh[t] - v;  // exclusive offset for (block t, bucket b)
    if (t == PA_BLOCKS - 1) bucket_cnt[b] = sh[t];
}

// ---- A3: replay edges; place src / dst&63 into split bucket slabs -----------
__global__ __launch_bounds__(256) void placeA_kernel(const int* __restrict__ src,
                                                     const int* __restrict__ dst,
                                                     const int* __restrict__ ph,
                                                     int* __restrict__ pairs_src,
                                                     unsigned char* __restrict__ pairs_dl,
                                                     int* __restrict__ ovfA_cnt,
                                                     int2* __restrict__ ovfA,
                                                     int E, int NB) {
    __shared__ int sbase[NBMAX];
    __shared__ int cur[NBMAX];
    int t = threadIdx.x;
    const int* row = ph + (size_t)blockIdx.x * NB;
    for (int b = t; b < NB; b += 256) { sbase[b] = row[b]; cur[b] = 0; }
    __syncthreads();
    int chunk = (E + gridDim.x - 1) / gridDim.x;
    int start = blockIdx.x * chunk;
    int end = min(start + chunk, E);
    for (int i = start + t; i < end; i += 256) {
        int dd = dst[i];
        int b = dd >> BSHIFT;
        int p = sbase[b] + atomicAdd(&cur[b], 1);
        if (p < BCAP) {
            pairs_src[(size_t)b * BCAP + p] = src[i];
            pairs_dl[(size_t)b * BCAP + p] = (unsigned char)(dd & (BSIZE - 1));
        } else {  // slab overflow (statistically never): spill, deg fixed later
            int q = atomicAdd(ovfA_cnt, 1);
            if (q < OVF_CAP) ovfA[q] = make_int2(dd, src[i]);
        }
    }
}

// ---- degB: per-bucket 64-counter histogram over pairs_dl -> global deg ------
__global__ __launch_bounds__(256) void degB_kernel(const unsigned char* __restrict__ pairs_dl,
                                                   const int* __restrict__ bucket_cnt,
                                                   int* __restrict__ deg, int N) {
    __shared__ int degL[BSIZE];
    int b = blockIdx.x, t = threadIdx.x;
    if (t < BSIZE) degL[t] = 0;
    __syncthreads();
    int cnt = min(bucket_cnt[b], BCAP);
    const unsigned char* pp = pairs_dl + (size_t)b * BCAP;
    for (int i = t; i < cnt; i += 256) atomicAdd(&degL[pp[i]], 1);
    __syncthreads();
    if (t < BSIZE) {
        int node = b * BSIZE + t;
        if (node < N) deg[node] = degL[t];
    }
}

// ---- deg fixup for A-phase spills (empty in practice) -----------------------
__global__ void degfix_kernel(const int* __restrict__ ovfA_cnt,
                              const int2* __restrict__ ovfA, int* __restrict__ deg) {
    int n = *ovfA_cnt;
    if (n > OVF_CAP) n = OVF_CAP;
    for (int k = threadIdx.x; k < n; k += blockDim.x)
        atomicAdd(&deg[ovfA[k].x], 1);
}

// ---------------- dinv = rsqrt(deg + 1 self-loop) ----------------
__global__ __launch_bounds__(256) void dinv_kernel(const int* __restrict__ deg,
                                                   float* __restrict__ dinv, int N) {
    int i = blockIdx.x * 256 + threadIdx.x;
    if (i < N) dinv[i] = rsqrtf((float)deg[i] + 1.0f);
}

// ---------------- xw = (x * dinv) @ W^T via MFMA f16, sigma-permuted cols -----
// xw[row] stored as 128 fp16 at half-index sigma(col) = (col%16)*8 + col/16.
// MFMA 16x16x32_f16: A[m=lane&15][k=(lane>>4)*8+j]; B[k][n=lane&15];
// D: col=lane&15, row=(lane>>4)*4+reg.
__global__ __launch_bounds__(256) void xw_kernel(const float* __restrict__ x,
                                                 const float* __restrict__ dinv,
                                                 const float* __restrict__ W,
                                                 __half* __restrict__ xw, int N) {
    __shared__ _Float16 Bf[128 * 128];  // 32 KB, fragment-ordered
    const int t = threadIdx.x;
    {
        int n = t >> 1;
        int jt = n >> 4, nlo = n & 15;
        int kbase = (t & 1) * 64;
#pragma unroll
        for (int o = 0; o < 8; ++o) {
            int k0 = kbase + o * 8;
            float4 f0 = *(const float4*)&W[n * 128 + k0];
            float4 f1 = *(const float4*)&W[n * 128 + k0 + 4];
            int kt = k0 >> 5, quad = (k0 >> 3) & 3;
            half8 h;
            h[0] = (_Float16)f0.x; h[1] = (_Float16)f0.y;
            h[2] = (_Float16)f0.z; h[3] = (_Float16)f0.w;
            h[4] = (_Float16)f1.x; h[5] = (_Float16)f1.y;
            h[6] = (_Float16)f1.z; h[7] = (_Float16)f1.w;
            *(half8*)&Bf[(size_t)(((kt * 8 + jt) * 4 + quad) * 16 + nlo) * 8] = h;
        }
    }
    __syncthreads();

    const int wave = t >> 6, lane = t & 63;
    const int quad = lane >> 4, nlo = lane & 15;
    const int r0 = blockIdx.x * 64 + wave * 16;
    const int rA = r0 + nlo;
    const int rAc = (rA < N) ? rA : (N - 1);
    const float dv = dinv[rAc];

    float4v acc[8];
#pragma unroll
    for (int j = 0; j < 8; ++j) acc[j] = (float4v){0.f, 0.f, 0.f, 0.f};

#pragma unroll
    for (int kt = 0; kt < 4; ++kt) {
        const float* xp = x + (size_t)rAc * D + kt * 32 + quad * 8;
        float4 a0 = *(const float4*)xp;
        float4 a1 = *(const float4*)(xp + 4);
        half8 va;
        va[0] = (_Float16)(a0.x * dv); va[1] = (_Float16)(a0.y * dv);
        va[2] = (_Float16)(a0.z * dv); va[3] = (_Float16)(a0.w * dv);
        va[4] = (_Float16)(a1.x * dv); va[5] = (_Float16)(a1.y * dv);
        va[6] = (_Float16)(a1.z * dv); va[7] = (_Float16)(a1.w * dv);
#pragma unroll
        for (int jt = 0; jt < 8; ++jt) {
            half8 vb = *(half8*)&Bf[(size_t)((kt * 8 + jt) * 64 + lane) * 8];
            acc[jt] = __builtin_amdgcn_mfma_f32_16x16x32_f16(va, vb, acc[jt], 0, 0, 0);
        }
    }

#pragma unroll
    for (int reg = 0; reg < 4; ++reg) {
        int row = r0 + quad * 4 + reg;
        if (row < N) {
            half8 h;
#pragma unroll
            for (int jt = 0; jt < 8; ++jt) h[jt] = (_Float16)acc[jt][reg];
            *(half8*)((_Float16*)xw + (size_t)row * D + nlo * 8) = h;
        }
    }
}

// ---------------- gatherB: in-block counting sort + gather + epilogue --------
// One block (16 waves) per bucket. Pairs held in registers across the sort.
// out[d][c] = x[d][c] + relu(dinv[d]*(xw[d] + sum_e xw[src_e]) + b[c])
// sigma-permuted: lane l's half2 = real cols c0=(l&3)*32+(l>>2), c1=c0+16.
__global__ __launch_bounds__(GB_THREADS) void gatherB_kernel(
    const float* __restrict__ x, const __half* __restrict__ xw,
    const int* __restrict__ pairs_src, const unsigned char* __restrict__ pairs_dl,
    const int* __restrict__ bucket_cnt, const float* __restrict__ dinv,
    const float* __restrict__ bias, const int* __restrict__ ovfA_cnt,
    const int2* __restrict__ ovfA, float* __restrict__ out, int N) {
    __shared__ int lds_src[BCAP];          // 12 KB
    __shared__ int degL[BSIZE], offs[BSIZE], cur[BSIZE];
    const int b = blockIdx.x;
    const int t = threadIdx.x;
    if (t < BSIZE) { degL[t] = 0; cur[t] = 0; }
    __syncthreads();
    const int cnt = min(bucket_cnt[b], BCAP);

    // stage 1a: load this thread's pairs into registers + LDS histogram
    int my_src[3], my_dl[3], my_n = 0;
    for (int i = t; i < cnt; i += GB_THREADS) {
        my_src[my_n] = pairs_src[(size_t)b * BCAP + i];
        my_dl[my_n] = pairs_dl[(size_t)b * BCAP + i];
        atomicAdd(&degL[my_dl[my_n]], 1);
        ++my_n;
    }
    __syncthreads();

    // stage 1b: exclusive scan of degL (wave 0, shuffle scan over 64 lanes)
    if (t < BSIZE) {
        int v = degL[t];
        int s = v;
#pragma unroll
        for (int o = 1; o < 64; o <<= 1) {
            int u = __shfl_up(s, o, 64);
            if (t >= o) s += u;
        }
        offs[t] = s - v;
    }
    __syncthreads();

    // stage 1c: scatter register-held pairs into node-sorted LDS list
    for (int k = 0; k < my_n; ++k) {
        int dl = my_dl[k];
        int p = atomicAdd(&cur[dl], 1);
        lds_src[offs[dl] + p] = my_src[k];
    }
    __syncthreads();

    // stage 2: wave w handles nodes dl = 4w..4w+3
    const int wave = t >> 6, lane = t & 63;
    const __half2* xw2 = (const __half2*)xw;
    int na = *ovfA_cnt;
    if (na > OVF_CAP) na = OVF_CAP;

    for (int q = 0; q < 4; ++q) {
        int dl = wave * 4 + q;
        int node = b * BSIZE + dl;
        if (node >= N) break;  // wave-uniform (dl is wave-uniform)
        int start = offs[dl];
        int end = start + degL[dl];
        float dvd = dinv[node];
        size_t noff = (size_t)node * D;

        float2 fs = __half22float2(xw2[(size_t)node * 64 + lane]);  // self term
        float s0 = fs.x, s1 = fs.y;

        int e = start;
        for (; e + 7 < end; e += 8) {
            int i0 = lds_src[e + 0], i1 = lds_src[e + 1];
            int i2 = lds_src[e + 2], i3 = lds_src[e + 3];
            int i4 = lds_src[e + 4], i5 = lds_src[e + 5];
            int i6 = lds_src[e + 6], i7 = lds_src[e + 7];
            float2 f0 = __half22float2(xw2[(size_t)i0 * 64 + lane]);
            float2 f1 = __half22float2(xw2[(size_t)i1 * 64 + lane]);
            float2 f2 = __half22float2(xw2[(size_t)i2 * 64 + lane]);
            float2 f3 = __half22float2(xw2[(size_t)i3 * 64 + lane]);
            float2 f4 = __half22float2(xw2[(size_t)i4 * 64 + lane]);
            float2 f5 = __half22float2(xw2[(size_t)i5 * 64 + lane]);
            float2 f6 = __half22float2(xw2[(size_t)i6 * 64 + lane]);
            float2 f7 = __half22float2(xw2[(size_t)i7 * 64 + lane]);
            s0 += (f0.x + f1.x) + (f2.x + f3.x) + ((f4.x + f5.x) + (f6.x + f7.x));
            s1 += (f0.y + f1.y) + (f2.y + f3.y) + ((f4.y + f5.y) + (f6.y + f7.y));
        }
        for (; e < end; ++e) {
            float2 f = __half22float2(xw2[(size_t)lds_src[e] * 64 + lane]);
            s0 += f.x;
            s1 += f.y;
        }

        // A-phase spill (statistically empty)
        if (na > 0) {
            for (int k = 0; k < na; ++k) {
                int2 pr = ovfA[k];
                if (pr.x == node) {
                    float2 f = __half22float2(xw2[(size_t)pr.y * 64 + lane]);
                    s0 += f.x; s1 += f.y;
                }
            }
        }

        int c0 = (lane & 3) * 32 + (lane >> 2);
        int c1 = c0 + 16;
        float h0 = s0 * dvd + bias[c0];
        float h1 = s1 * dvd + bias[c1];
        out[noff + c0] = x[noff + c0] + (h0 > 0.f ? h0 : 0.f);
        out[noff + c1] = x[noff + c1] + (h1 > 0.f ? h1 : 0.f);
    }
}

extern "C" void kernel_launch(void* const* d_in, const int* in_sizes, int n_in,
                              void* d_out, int out_size, void* d_ws, size_t ws_size,
                              hipStream_t stream) {
    const float* x = (const float*)d_in[0];
    const int* ei = (const int*)d_in[1];
    const float* W = (const float*)d_in[2];
    const float* bias = (const float*)d_in[3];
    float* out = (float*)d_out;

    const int N = in_sizes[0] / D;   // 50000
    const int E = in_sizes[1] / 2;   // 1,600,000
    const int* src = ei;
    const int* dst = ei + E;
    const int NB = (N + BSIZE - 1) / BSIZE;  // 782 (<= NBMAX)

    // workspace (~27 MB)
    char* p = (char*)d_ws;
    int* pairs_src = (int*)p;           p += (size_t)NB * BCAP * sizeof(int);  // 9.6 MB
    unsigned char* pairs_dl = (unsigned char*)p; p += (size_t)NB * BCAP;       // 2.4 MB
    p = (char*)(((size_t)p + 15) & ~(size_t)15);
    __half* xw = (__half*)p;            p += (size_t)N * D * sizeof(__half);   // 12.8 MB
    int* deg = (int*)p;                 p += (size_t)N * sizeof(int);
    float* dinv = (float*)p;            p += (size_t)N * sizeof(float);
    int* bucket_cnt = (int*)p;          p += (size_t)NBMAX * sizeof(int);
    int* ovfA_cnt = (int*)p;            p += 16;
    int2* ovfA = (int2*)p;              p += (size_t)OVF_CAP * sizeof(int2);   // 0.5 MB
    int* ph = (int*)p;                  p += (size_t)PA_BLOCKS * NB * sizeof(int); // 0.8 MB

    hipMemsetAsync(ovfA_cnt, 0, 16, stream);  // only the spill counter

    histA_kernel<<<PA_BLOCKS, 256, 0, stream>>>(dst, ph, E, NB);
    scanA_kernel<<<NB, PA_BLOCKS, 0, stream>>>(ph, bucket_cnt, NB);
    placeA_kernel<<<PA_BLOCKS, 256, 0, stream>>>(src, dst, ph, pairs_src, pairs_dl,
                                                 ovfA_cnt, ovfA, E, NB);
    degB_kernel<<<NB, 256, 0, stream>>>(pairs_dl, bucket_cnt, deg, N);
    degfix_kernel<<<1, 256, 0, stream>>>(ovfA_cnt, ovfA, deg);
    dinv_kernel<<<(N + 255) / 256, 256, 0, stream>>>(deg, dinv, N);
    xw_kernel<<<(N + 63) / 64, 256, 0, stream>>>(x, dinv, W, xw, N);
    gatherB_kernel<<<NB, GB_THREADS, 0, stream>>>(x, xw, pairs_src, pairs_dl,
                                                  bucket_cnt, dinv, bias,
                                                  ovfA_cnt, ovfA, out, N);
}

// Round 10
// 185.839 us; speedup vs baseline: 1.1642x; 1.1642x over previous
//
#include <hip/hip_runtime.h>
#include <hip/hip_fp16.h>

#define D 128
#define BSHIFT 6
#define BSIZE 64         // nodes per bucket
#define NBMAX 1024       // supports N <= 65536 (and N <= 2^26 for packing)
#define BCAP 3072        // slab capacity per bucket (E[cnt]=2046, >20 sigma safe)
#define PA_BLOCKS 256
#define OVF_CAP 65536
#define GB_THREADS 1024  // gatherB block: 16 waves, one bucket per block

using half8 = __attribute__((ext_vector_type(8))) _Float16;
using float4v = __attribute__((ext_vector_type(4))) float;

// ---- A1: per-block LDS histogram of dst>>6; write block-major partials ------
__global__ __launch_bounds__(256) void histA_kernel(const int* __restrict__ dst,
                                                    int* __restrict__ ph, int E, int NB) {
    __shared__ int hist[NBMAX];
    int t = threadIdx.x;
    for (int b = t; b < NB; b += 256) hist[b] = 0;
    __syncthreads();
    int chunk = (((E + (int)gridDim.x - 1) / (int)gridDim.x) + 3) & ~3;  // 4-aligned
    int start = blockIdx.x * chunk;
    int end = min(start + chunk, E);
    for (int i = start + 4 * t; i < end; i += 4 * 256) {
        if (i + 3 < end) {
            int4 v = *(const int4*)&dst[i];
            atomicAdd(&hist[v.x >> BSHIFT], 1);
            atomicAdd(&hist[v.y >> BSHIFT], 1);
            atomicAdd(&hist[v.z >> BSHIFT], 1);
            atomicAdd(&hist[v.w >> BSHIFT], 1);
        } else {
            for (int j = i; j < end; ++j) atomicAdd(&hist[dst[j] >> BSHIFT], 1);
        }
    }
    __syncthreads();
    int* row = ph + (size_t)blockIdx.x * NB;
    for (int b = t; b < NB; b += 256) row[b] = hist[b];
}

// ---- A2: per-bucket exclusive scan over the 256 block partials --------------
__global__ __launch_bounds__(PA_BLOCKS) void scanA_kernel(int* __restrict__ ph,
                                                          int* __restrict__ bucket_cnt,
                                                          int NB) {
    __shared__ int sh[PA_BLOCKS];
    int b = blockIdx.x;
    int t = threadIdx.x;
    int v = ph[(size_t)t * NB + b];
    sh[t] = v;
    __syncthreads();
    for (int off = 1; off < PA_BLOCKS; off <<= 1) {
        int add = (t >= off) ? sh[t - off] : 0;
        __syncthreads();
        sh[t] += add;
        __syncthreads();
    }
    ph[(size_t)t * NB + b] = sh[t] - v;  // exclusive offset for (block t, bucket b)
    if (t == PA_BLOCKS - 1) bucket_cnt[b] = sh[t];
}

// ---- A3: replay edges; place packed (src<<6)|dl into bucket slabs -----------
__global__ __launch_bounds__(256) void placeA_kernel(const int* __restrict__ src,
                                                     const int* __restrict__ dst,
                                                     const int* __restrict__ ph,
                                                     int* __restrict__ pairs,
                                                     int* __restrict__ ovfA_cnt,
                                                     int2* __restrict__ ovfA,
                                                     int E, int NB) {
    __shared__ int sbase[NBMAX];
    __shared__ int cur[NBMAX];
    int t = threadIdx.x;
    const int* row = ph + (size_t)blockIdx.x * NB;
    for (int b = t; b < NB; b += 256) { sbase[b] = row[b]; cur[b] = 0; }
    __syncthreads();
    int chunk = (((E + (int)gridDim.x - 1) / (int)gridDim.x) + 3) & ~3;
    int start = blockIdx.x * chunk;
    int end = min(start + chunk, E);

    auto place = [&](int dd, int ss) {
        int b = dd >> BSHIFT;
        int p = sbase[b] + atomicAdd(&cur[b], 1);
        if (p < BCAP) {
            pairs[(size_t)b * BCAP + p] = (ss << BSHIFT) | (dd & (BSIZE - 1));
        } else {  // slab overflow (statistically never)
            int q = atomicAdd(ovfA_cnt, 1);
            if (q < OVF_CAP) ovfA[q] = make_int2(dd, ss);
        }
    };

    for (int i = start + 4 * t; i < end; i += 4 * 256) {
        if (i + 3 < end) {
            int4 dv = *(const int4*)&dst[i];
            int4 sv = *(const int4*)&src[i];
            place(dv.x, sv.x);
            place(dv.y, sv.y);
            place(dv.z, sv.z);
            place(dv.w, sv.w);
        } else {
            for (int j = i; j < end; ++j) place(dst[j], src[j]);
        }
    }
}

// ---- degB: per-bucket histogram (incl. spills) -> dinv directly -------------
__global__ __launch_bounds__(256) void degB_kernel(const int* __restrict__ pairs,
                                                   const int* __restrict__ bucket_cnt,
                                                   const int* __restrict__ ovfA_cnt,
                                                   const int2* __restrict__ ovfA,
                                                   float* __restrict__ dinv, int N) {
    __shared__ int degL[BSIZE];
    int b = blockIdx.x, t = threadIdx.x;
    if (t < BSIZE) degL[t] = 0;
    __syncthreads();
    int cnt = min(bucket_cnt[b], BCAP);
    const int* pp = pairs + (size_t)b * BCAP;
    for (int i = t; i < cnt; i += 256) atomicAdd(&degL[pp[i] & (BSIZE - 1)], 1);
    int na = *ovfA_cnt;  // statistically 0
    if (na > 0) {
        if (na > OVF_CAP) na = OVF_CAP;
        for (int k = t; k < na; k += 256) {
            int dd = ovfA[k].x;
            if ((dd >> BSHIFT) == b) atomicAdd(&degL[dd & (BSIZE - 1)], 1);
        }
    }
    __syncthreads();
    if (t < BSIZE) {
        int node = b * BSIZE + t;
        if (node < N) dinv[node] = rsqrtf((float)degL[t] + 1.0f);
    }
}

// ---------------- xw = (x * dinv) @ W^T via MFMA f16, sigma-permuted cols -----
// xw[row] stored as 128 fp16 at half-index sigma(col) = (col%16)*8 + col/16.
// MFMA 16x16x32_f16: A[m=lane&15][k=(lane>>4)*8+j]; B[k][n=lane&15];
// D: col=lane&15, row=(lane>>4)*4+reg.
__global__ __launch_bounds__(256) void xw_kernel(const float* __restrict__ x,
                                                 const float* __restrict__ dinv,
                                                 const float* __restrict__ W,
                                                 __half* __restrict__ xw, int N) {
    __shared__ _Float16 Bf[128 * 128];  // 32 KB, fragment-ordered
    const int t = threadIdx.x;
    {
        int n = t >> 1;
        int jt = n >> 4, nlo = n & 15;
        int kbase = (t & 1) * 64;
#pragma unroll
        for (int o = 0; o < 8; ++o) {
            int k0 = kbase + o * 8;
            float4 f0 = *(const float4*)&W[n * 128 + k0];
            float4 f1 = *(const float4*)&W[n * 128 + k0 + 4];
            int kt = k0 >> 5, quad = (k0 >> 3) & 3;
            half8 h;
            h[0] = (_Float16)f0.x; h[1] = (_Float16)f0.y;
            h[2] = (_Float16)f0.z; h[3] = (_Float16)f0.w;
            h[4] = (_Float16)f1.x; h[5] = (_Float16)f1.y;
            h[6] = (_Float16)f1.z; h[7] = (_Float16)f1.w;
            *(half8*)&Bf[(size_t)(((kt * 8 + jt) * 4 + quad) * 16 + nlo) * 8] = h;
        }
    }
    __syncthreads();

    const int wave = t >> 6, lane = t & 63;
    const int quad = lane >> 4, nlo = lane & 15;
    const int r0 = blockIdx.x * 64 + wave * 16;
    const int rA = r0 + nlo;
    const int rAc = (rA < N) ? rA : (N - 1);
    const float dv = dinv[rAc];

    float4v acc[8];
#pragma unroll
    for (int j = 0; j < 8; ++j) acc[j] = (float4v){0.f, 0.f, 0.f, 0.f};

#pragma unroll
    for (int kt = 0; kt < 4; ++kt) {
        const float* xp = x + (size_t)rAc * D + kt * 32 + quad * 8;
        float4 a0 = *(const float4*)xp;
        float4 a1 = *(const float4*)(xp + 4);
        half8 va;
        va[0] = (_Float16)(a0.x * dv); va[1] = (_Float16)(a0.y * dv);
        va[2] = (_Float16)(a0.z * dv); va[3] = (_Float16)(a0.w * dv);
        va[4] = (_Float16)(a1.x * dv); va[5] = (_Float16)(a1.y * dv);
        va[6] = (_Float16)(a1.z * dv); va[7] = (_Float16)(a1.w * dv);
#pragma unroll
        for (int jt = 0; jt < 8; ++jt) {
            half8 vb = *(half8*)&Bf[(size_t)((kt * 8 + jt) * 64 + lane) * 8];
            acc[jt] = __builtin_amdgcn_mfma_f32_16x16x32_f16(va, vb, acc[jt], 0, 0, 0);
        }
    }

#pragma unroll
    for (int reg = 0; reg < 4; ++reg) {
        int row = r0 + quad * 4 + reg;
        if (row < N) {
            half8 h;
#pragma unroll
            for (int jt = 0; jt < 8; ++jt) h[jt] = (_Float16)acc[jt][reg];
            *(half8*)((_Float16*)xw + (size_t)row * D + nlo * 8) = h;
        }
    }
}

// ---------------- gatherB: in-block counting sort + gather + epilogue --------
// One block (16 waves) per bucket. Packed pairs held in registers across sort.
// out[d][c] = x[d][c] + relu(dinv[d]*(xw[d] + sum_e xw[src_e]) + b[c])
// sigma-permuted: lane l's half2 = real cols c0=(l&3)*32+(l>>2), c1=c0+16.
__global__ __launch_bounds__(GB_THREADS) void gatherB_kernel(
    const float* __restrict__ x, const __half* __restrict__ xw,
    const int* __restrict__ pairs, const int* __restrict__ bucket_cnt,
    const float* __restrict__ dinv, const float* __restrict__ bias,
    const int* __restrict__ ovfA_cnt, const int2* __restrict__ ovfA,
    float* __restrict__ out, int N) {
    __shared__ int lds_src[BCAP];          // 12 KB
    __shared__ int degL[BSIZE], offs[BSIZE], cur[BSIZE];
    const int b = blockIdx.x;
    const int t = threadIdx.x;
    if (t < BSIZE) { degL[t] = 0; cur[t] = 0; }
    __syncthreads();
    const int cnt = min(bucket_cnt[b], BCAP);

    // stage 1a: load packed pairs into registers + LDS histogram
    int my_w[3], my_n = 0;
    for (int i = t; i < cnt; i += GB_THREADS) {
        int w = pairs[(size_t)b * BCAP + i];
        my_w[my_n++] = w;
        atomicAdd(&degL[w & (BSIZE - 1)], 1);
    }
    __syncthreads();

    // stage 1b: exclusive scan of degL (wave 0, shuffle scan over 64 lanes)
    if (t < BSIZE) {
        int v = degL[t];
        int s = v;
#pragma unroll
        for (int o = 1; o < 64; o <<= 1) {
            int u = __shfl_up(s, o, 64);
            if (t >= o) s += u;
        }
        offs[t] = s - v;
    }
    __syncthreads();

    // stage 1c: scatter register-held pairs into node-sorted LDS list
    for (int k = 0; k < my_n; ++k) {
        int w = my_w[k];
        int dl = w & (BSIZE - 1);
        int p = atomicAdd(&cur[dl], 1);
        lds_src[offs[dl] + p] = w >> BSHIFT;
    }
    __syncthreads();

    // stage 2: wave w handles nodes dl = 4w..4w+3
    const int wave = t >> 6, lane = t & 63;
    const __half2* xw2 = (const __half2*)xw;
    int na = *ovfA_cnt;
    if (na > OVF_CAP) na = OVF_CAP;

    for (int q = 0; q < 4; ++q) {
        int dl = wave * 4 + q;
        int node = b * BSIZE + dl;
        if (node >= N) break;  // wave-uniform (dl is wave-uniform)
        int start = offs[dl];
        int end = start + degL[dl];
        float dvd = dinv[node];
        size_t noff = (size_t)node * D;

        float2 fs = __half22float2(xw2[(size_t)node * 64 + lane]);  // self term
        float s0 = fs.x, s1 = fs.y;

        int e = start;
        for (; e + 7 < end; e += 8) {
            int i0 = lds_src[e + 0], i1 = lds_src[e + 1];
            int i2 = lds_src[e + 2], i3 = lds_src[e + 3];
            int i4 = lds_src[e + 4], i5 = lds_src[e + 5];
            int i6 = lds_src[e + 6], i7 = lds_src[e + 7];
            float2 f0 = __half22float2(xw2[(size_t)i0 * 64 + lane]);
            float2 f1 = __half22float2(xw2[(size_t)i1 * 64 + lane]);
            float2 f2 = __half22float2(xw2[(size_t)i2 * 64 + lane]);
            float2 f3 = __half22float2(xw2[(size_t)i3 * 64 + lane]);
            float2 f4 = __half22float2(xw2[(size_t)i4 * 64 + lane]);
            float2 f5 = __half22float2(xw2[(size_t)i5 * 64 + lane]);
            float2 f6 = __half22float2(xw2[(size_t)i6 * 64 + lane]);
            float2 f7 = __half22float2(xw2[(size_t)i7 * 64 + lane]);
            s0 += (f0.x + f1.x) + (f2.x + f3.x) + ((f4.x + f5.x) + (f6.x + f7.x));
            s1 += (f0.y + f1.y) + (f2.y + f3.y) + ((f4.y + f5.y) + (f6.y + f7.y));
        }
        for (; e < end; ++e) {
            float2 f = __half22float2(xw2[(size_t)lds_src[e] * 64 + lane]);
            s0 += f.x;
            s1 += f.y;
        }

        // A-phase spill (statistically empty)
        if (na > 0) {
            for (int k = 0; k < na; ++k) {
                int2 pr = ovfA[k];
                if (pr.x == node) {
                    float2 f = __half22float2(xw2[(size_t)pr.y * 64 + lane]);
                    s0 += f.x; s1 += f.y;
                }
            }
        }

        int c0 = (lane & 3) * 32 + (lane >> 2);
        int c1 = c0 + 16;
        float h0 = s0 * dvd + bias[c0];
        float h1 = s1 * dvd + bias[c1];
        out[noff + c0] = x[noff + c0] + (h0 > 0.f ? h0 : 0.f);
        out[noff + c1] = x[noff + c1] + (h1 > 0.f ? h1 : 0.f);
    }
}

extern "C" void kernel_launch(void* const* d_in, const int* in_sizes, int n_in,
                              void* d_out, int out_size, void* d_ws, size_t ws_size,
                              hipStream_t stream) {
    const float* x = (const float*)d_in[0];
    const int* ei = (const int*)d_in[1];
    const float* W = (const float*)d_in[2];
    const float* bias = (const float*)d_in[3];
    float* out = (float*)d_out;

    const int N = in_sizes[0] / D;   // 50000
    const int E = in_sizes[1] / 2;   // 1,600,000
    const int* src = ei;
    const int* dst = ei + E;
    const int NB = (N + BSIZE - 1) / BSIZE;  // 782 (<= NBMAX)

    // workspace (~24 MB)
    char* p = (char*)d_ws;
    int* pairs = (int*)p;      p += (size_t)NB * BCAP * sizeof(int);      // 9.6 MB
    __half* xw = (__half*)p;   p += (size_t)N * D * sizeof(__half);       // 12.8 MB
    float* dinv = (float*)p;   p += (size_t)N * sizeof(float);
    int* bucket_cnt = (int*)p; p += (size_t)NBMAX * sizeof(int);
    int* ovfA_cnt = (int*)p;   p += 16;
    int2* ovfA = (int2*)p;     p += (size_t)OVF_CAP * sizeof(int2);       // 0.5 MB
    int* ph = (int*)p;         p += (size_t)PA_BLOCKS * NB * sizeof(int); // 0.8 MB

    hipMemsetAsync(ovfA_cnt, 0, 16, stream);  // only the spill counter

    histA_kernel<<<PA_BLOCKS, 256, 0, stream>>>(dst, ph, E, NB);
    scanA_kernel<<<NB, PA_BLOCKS, 0, stream>>>(ph, bucket_cnt, NB);
    placeA_kernel<<<PA_BLOCKS, 256, 0, stream>>>(src, dst, ph, pairs,
                                                 ovfA_cnt, ovfA, E, NB);
    degB_kernel<<<NB, 256, 0, stream>>>(pairs, bucket_cnt, ovfA_cnt, ovfA, dinv, N);
    xw_kernel<<<(N + 63) / 64, 256, 0, stream>>>(x, dinv, W, xw, N);
    gatherB_kernel<<<NB, GB_THREADS, 0, stream>>>(x, xw, pairs, bucket_cnt,
                                                  dinv, bias, ovfA_cnt, ovfA,
                                                  out, N);
}

// Round 11
// 160.347 us; speedup vs baseline: 1.3493x; 1.1590x over previous
//
#include <hip/hip_runtime.h>
#include <hip/hip_fp16.h>

#define D 128
#define BSHIFT 6
#define BSIZE 64         // nodes per bucket
#define NBMAX 1024       // supports N <= 65536 (and N <= 2^26 for packing)
#define BCAP 3072        // slab capacity per bucket (E[cnt]=2046, >20 sigma safe)
#define PA_BLOCKS 256
#define OVF_CAP 65536
#define GB_THREADS 1024  // gatherB block: 16 waves, one bucket per block

using half8 = __attribute__((ext_vector_type(8))) _Float16;
using float4v = __attribute__((ext_vector_type(4))) float;
using floatx2 = __attribute__((ext_vector_type(2))) float;

// ---- A1: per-block LDS histogram of dst>>6; write block-major partials ------
__global__ __launch_bounds__(256) void histA_kernel(const int* __restrict__ dst,
                                                    int* __restrict__ ph, int E, int NB) {
    __shared__ int hist[NBMAX];
    int t = threadIdx.x;
    for (int b = t; b < NB; b += 256) hist[b] = 0;
    __syncthreads();
    int chunk = (((E + (int)gridDim.x - 1) / (int)gridDim.x) + 3) & ~3;  // 4-aligned
    int start = blockIdx.x * chunk;
    int end = min(start + chunk, E);
    for (int i = start + 4 * t; i < end; i += 4 * 256) {
        if (i + 3 < end) {
            int4 v = *(const int4*)&dst[i];
            atomicAdd(&hist[v.x >> BSHIFT], 1);
            atomicAdd(&hist[v.y >> BSHIFT], 1);
            atomicAdd(&hist[v.z >> BSHIFT], 1);
            atomicAdd(&hist[v.w >> BSHIFT], 1);
        } else {
            for (int j = i; j < end; ++j) atomicAdd(&hist[dst[j] >> BSHIFT], 1);
        }
    }
    __syncthreads();
    int* row = ph + (size_t)blockIdx.x * NB;
    for (int b = t; b < NB; b += 256) row[b] = hist[b];
}

// ---- A2: per-bucket exclusive scan over the 256 block partials --------------
__global__ __launch_bounds__(PA_BLOCKS) void scanA_kernel(int* __restrict__ ph,
                                                          int* __restrict__ bucket_cnt,
                                                          int NB) {
    __shared__ int sh[PA_BLOCKS];
    int b = blockIdx.x;
    int t = threadIdx.x;
    int v = ph[(size_t)t * NB + b];
    sh[t] = v;
    __syncthreads();
    for (int off = 1; off < PA_BLOCKS; off <<= 1) {
        int add = (t >= off) ? sh[t - off] : 0;
        __syncthreads();
        sh[t] += add;
        __syncthreads();
    }
    ph[(size_t)t * NB + b] = sh[t] - v;  // exclusive offset for (block t, bucket b)
    if (t == PA_BLOCKS - 1) bucket_cnt[b] = sh[t];
}

// ---- A3: replay edges; place packed (src<<6)|dl into bucket slabs -----------
__global__ __launch_bounds__(256) void placeA_kernel(const int* __restrict__ src,
                                                     const int* __restrict__ dst,
                                                     const int* __restrict__ ph,
                                                     int* __restrict__ pairs,
                                                     int* __restrict__ ovfA_cnt,
                                                     int2* __restrict__ ovfA,
                                                     int E, int NB) {
    __shared__ int sbase[NBMAX];
    __shared__ int cur[NBMAX];
    int t = threadIdx.x;
    const int* row = ph + (size_t)blockIdx.x * NB;
    for (int b = t; b < NB; b += 256) { sbase[b] = row[b]; cur[b] = 0; }
    __syncthreads();
    int chunk = (((E + (int)gridDim.x - 1) / (int)gridDim.x) + 3) & ~3;
    int start = blockIdx.x * chunk;
    int end = min(start + chunk, E);

    auto place = [&](int dd, int ss) {
        int b = dd >> BSHIFT;
        int p = sbase[b] + atomicAdd(&cur[b], 1);
        if (p < BCAP) {
            pairs[(size_t)b * BCAP + p] = (ss << BSHIFT) | (dd & (BSIZE - 1));
        } else {  // slab overflow (statistically never)
            int q = atomicAdd(ovfA_cnt, 1);
            if (q < OVF_CAP) ovfA[q] = make_int2(dd, ss);
        }
    };

    for (int i = start + 4 * t; i < end; i += 4 * 256) {
        if (i + 3 < end) {
            int4 dv = *(const int4*)&dst[i];
            int4 sv = *(const int4*)&src[i];
            place(dv.x, sv.x);
            place(dv.y, sv.y);
            place(dv.z, sv.z);
            place(dv.w, sv.w);
        } else {
            for (int j = i; j < end; ++j) place(dst[j], src[j]);
        }
    }
}

// ---------------- xw = (x * dinv) @ W^T via MFMA f16 -> fp8 e4m3, sigma cols --
// Block b handles rows b*64..b*64+63 == bucket b's nodes; dinv computed locally
// from the bucket's pairs slab (+ spills). xw[row] = 128 fp8 bytes at byte index
// sigma(col) = (col%16)*8 + col/16.
// MFMA 16x16x32_f16: A[m=lane&15][k=(lane>>4)*8+j]; B[k][n=lane&15];
// D: col=lane&15, row=(lane>>4)*4+reg.
__global__ __launch_bounds__(256) void xw_kernel(const float* __restrict__ x,
                                                 const float* __restrict__ W,
                                                 const int* __restrict__ pairs,
                                                 const int* __restrict__ bucket_cnt,
                                                 const int* __restrict__ ovfA_cnt,
                                                 const int2* __restrict__ ovfA,
                                                 unsigned char* __restrict__ xw, int N) {
    __shared__ _Float16 Bf[128 * 128];  // 32 KB, fragment-ordered
    __shared__ int degX[BSIZE];
    const int t = threadIdx.x;
    const int b = blockIdx.x;
    if (t < BSIZE) degX[t] = 0;
    __syncthreads();

    // degree histogram for this bucket (for dinv)
    {
        int cnt = min(bucket_cnt[b], BCAP);
        const int* pp = pairs + (size_t)b * BCAP;
        for (int i = t; i < cnt; i += 256) atomicAdd(&degX[pp[i] & (BSIZE - 1)], 1);
        int na = *ovfA_cnt;
        if (na > 0) {
            if (na > OVF_CAP) na = OVF_CAP;
            for (int k = t; k < na; k += 256) {
                int dd = ovfA[k].x;
                if ((dd >> BSHIFT) == b) atomicAdd(&degX[dd & (BSIZE - 1)], 1);
            }
        }
    }

    // stage B fragments
    {
        int n = t >> 1;
        int jt = n >> 4, nlo = n & 15;
        int kbase = (t & 1) * 64;
#pragma unroll
        for (int o = 0; o < 8; ++o) {
            int k0 = kbase + o * 8;
            float4 f0 = *(const float4*)&W[n * 128 + k0];
            float4 f1 = *(const float4*)&W[n * 128 + k0 + 4];
            int kt = k0 >> 5, quad = (k0 >> 3) & 3;
            half8 h;
            h[0] = (_Float16)f0.x; h[1] = (_Float16)f0.y;
            h[2] = (_Float16)f0.z; h[3] = (_Float16)f0.w;
            h[4] = (_Float16)f1.x; h[5] = (_Float16)f1.y;
            h[6] = (_Float16)f1.z; h[7] = (_Float16)f1.w;
            *(half8*)&Bf[(size_t)(((kt * 8 + jt) * 4 + quad) * 16 + nlo) * 8] = h;
        }
    }
    __syncthreads();

    const int wave = t >> 6, lane = t & 63;
    const int quad = lane >> 4, nlo = lane & 15;
    const int r0 = b * 64 + wave * 16;
    const int rA = r0 + nlo;
    const int rAc = (rA < N) ? rA : (N - 1);
    const float dv = rsqrtf((float)degX[rAc - b * 64] + 1.0f);

    float4v acc[8];
#pragma unroll
    for (int j = 0; j < 8; ++j) acc[j] = (float4v){0.f, 0.f, 0.f, 0.f};

#pragma unroll
    for (int kt = 0; kt < 4; ++kt) {
        const float* xp = x + (size_t)rAc * D + kt * 32 + quad * 8;
        float4 a0 = *(const float4*)xp;
        float4 a1 = *(const float4*)(xp + 4);
        half8 va;
        va[0] = (_Float16)(a0.x * dv); va[1] = (_Float16)(a0.y * dv);
        va[2] = (_Float16)(a0.z * dv); va[3] = (_Float16)(a0.w * dv);
        va[4] = (_Float16)(a1.x * dv); va[5] = (_Float16)(a1.y * dv);
        va[6] = (_Float16)(a1.z * dv); va[7] = (_Float16)(a1.w * dv);
#pragma unroll
        for (int jt = 0; jt < 8; ++jt) {
            half8 vb = *(half8*)&Bf[(size_t)((kt * 8 + jt) * 64 + lane) * 8];
            acc[jt] = __builtin_amdgcn_mfma_f32_16x16x32_f16(va, vb, acc[jt], 0, 0, 0);
        }
    }

    // store fp8: lane's 8 jt-values -> bytes nlo*8 .. nlo*8+7 of row
#pragma unroll
    for (int reg = 0; reg < 4; ++reg) {
        int row = r0 + quad * 4 + reg;
        if (row < N) {
            int u0 = __builtin_amdgcn_cvt_pk_fp8_f32(acc[0][reg], acc[1][reg], 0, false);
            u0 = __builtin_amdgcn_cvt_pk_fp8_f32(acc[2][reg], acc[3][reg], u0, true);
            int u1 = __builtin_amdgcn_cvt_pk_fp8_f32(acc[4][reg], acc[5][reg], 0, false);
            u1 = __builtin_amdgcn_cvt_pk_fp8_f32(acc[6][reg], acc[7][reg], u1, true);
            *(uint2*)(xw + (size_t)row * 128 + nlo * 8) = make_uint2((unsigned)u0, (unsigned)u1);
        }
    }
}

// ---------------- gatherB: in-block counting sort + fp8 gather + epilogue ----
// One block (16 waves) per bucket. Two edges per wave-pass: lanes 0-31 edge e,
// lanes 32-63 edge e+1, 4 fp8 cols per lane; shfl_xor(32) combine at the end.
// out[d][c] = x[d][c] + relu(dinv[d]*(xw[d] + sum_e xw[src_e]) + b[c])
// byte s of a row = col ((s%8)*16 + s/8).
__global__ __launch_bounds__(GB_THREADS) void gatherB_kernel(
    const float* __restrict__ x, const unsigned char* __restrict__ xw,
    const int* __restrict__ pairs, const int* __restrict__ bucket_cnt,
    const float* __restrict__ bias, const int* __restrict__ ovfA_cnt,
    const int2* __restrict__ ovfA, float* __restrict__ out, int N) {
    __shared__ int lds_src[BCAP];          // 12 KB
    __shared__ int degL[BSIZE], offs[BSIZE], cur[BSIZE], spillc[BSIZE];
    const int b = blockIdx.x;
    const int t = threadIdx.x;
    if (t < BSIZE) { degL[t] = 0; cur[t] = 0; spillc[t] = 0; }
    __syncthreads();
    const int cnt = min(bucket_cnt[b], BCAP);
    int na = *ovfA_cnt;
    if (na > OVF_CAP) na = OVF_CAP;

    // stage 1a: load packed pairs into registers + LDS histogram (slab only)
    int my_w[3], my_n = 0;
    for (int i = t; i < cnt; i += GB_THREADS) {
        int w = pairs[(size_t)b * BCAP + i];
        my_w[my_n++] = w;
        atomicAdd(&degL[w & (BSIZE - 1)], 1);
    }
    // spill counts go to a separate array (dinv only; NOT the LDS list offsets)
    if (na > 0) {
        for (int k = t; k < na; k += GB_THREADS) {
            int dd = ovfA[k].x;
            if ((dd >> BSHIFT) == b) atomicAdd(&spillc[dd & (BSIZE - 1)], 1);
        }
    }
    __syncthreads();

    // stage 1b: exclusive scan of degL (wave 0, shuffle scan over 64 lanes)
    if (t < BSIZE) {
        int v = degL[t];
        int s = v;
#pragma unroll
        for (int o = 1; o < 64; o <<= 1) {
            int u = __shfl_up(s, o, 64);
            if (t >= o) s += u;
        }
        offs[t] = s - v;
    }
    __syncthreads();

    // stage 1c: scatter register-held pairs into node-sorted LDS list
    for (int k = 0; k < my_n; ++k) {
        int w = my_w[k];
        int dl = w & (BSIZE - 1);
        int p = atomicAdd(&cur[dl], 1);
        lds_src[offs[dl] + p] = w >> BSHIFT;
    }
    __syncthreads();

    // stage 2: wave w handles nodes dl = 4w..4w+3
    const int wave = t >> 6, lane = t & 63;
    const int half = lane >> 5, c31 = lane & 31;
    const unsigned int* xw32 = (const unsigned int*)xw;  // row r at r*32 + c31

    // column map for this lane's 4 fp8 bytes (s = 4*c31+k)
    int col[4];
    float bcol[4];
#pragma unroll
    for (int k = 0; k < 4; ++k) {
        int s = 4 * c31 + k;
        col[k] = ((s & 7) << 4) + (s >> 3);
        bcol[k] = bias[col[k]];
    }

    for (int q = 0; q < 4; ++q) {
        int dl = wave * 4 + q;
        int node = b * BSIZE + dl;
        if (node >= N) break;  // wave-uniform
        int start = offs[dl];
        int end = start + degL[dl];
        float dvd = rsqrtf((float)(degL[dl] + spillc[dl]) + 1.0f);
        size_t noff = (size_t)node * D;

        float a0 = 0.f, a1 = 0.f, a2 = 0.f, a3 = 0.f;

        int e = start;
        for (; e + 7 < end; e += 8) {
            int r0 = lds_src[e + 0 + half], r1 = lds_src[e + 2 + half];
            int r2 = lds_src[e + 4 + half], r3 = lds_src[e + 6 + half];
            unsigned int w0 = xw32[(size_t)r0 * 32 + c31];
            unsigned int w1 = xw32[(size_t)r1 * 32 + c31];
            unsigned int w2 = xw32[(size_t)r2 * 32 + c31];
            unsigned int w3 = xw32[(size_t)r3 * 32 + c31];
            floatx2 l0 = __builtin_amdgcn_cvt_pk_f32_fp8((int)w0, false);
            floatx2 h0 = __builtin_amdgcn_cvt_pk_f32_fp8((int)w0, true);
            floatx2 l1 = __builtin_amdgcn_cvt_pk_f32_fp8((int)w1, false);
            floatx2 h1 = __builtin_amdgcn_cvt_pk_f32_fp8((int)w1, true);
            floatx2 l2 = __builtin_amdgcn_cvt_pk_f32_fp8((int)w2, false);
            floatx2 h2 = __builtin_amdgcn_cvt_pk_f32_fp8((int)w2, true);
            floatx2 l3 = __builtin_amdgcn_cvt_pk_f32_fp8((int)w3, false);
            floatx2 h3 = __builtin_amdgcn_cvt_pk_f32_fp8((int)w3, true);
            a0 += (l0.x + l1.x) + (l2.x + l3.x);
            a1 += (l0.y + l1.y) + (l2.y + l3.y);
            a2 += (h0.x + h1.x) + (h2.x + h3.x);
            a3 += (h0.y + h1.y) + (h2.y + h3.y);
        }
        for (; e + 1 < end; e += 2) {
            int r = lds_src[e + half];
            unsigned int w = xw32[(size_t)r * 32 + c31];
            floatx2 lo = __builtin_amdgcn_cvt_pk_f32_fp8((int)w, false);
            floatx2 hi = __builtin_amdgcn_cvt_pk_f32_fp8((int)w, true);
            a0 += lo.x; a1 += lo.y; a2 += hi.x; a3 += hi.y;
        }
        if (e < end && half == 0) {  // odd tail: lanes 0-31 only
            int r = lds_src[e];
            unsigned int w = xw32[(size_t)r * 32 + c31];
            floatx2 lo = __builtin_amdgcn_cvt_pk_f32_fp8((int)w, false);
            floatx2 hi = __builtin_amdgcn_cvt_pk_f32_fp8((int)w, true);
            a0 += lo.x; a1 += lo.y; a2 += hi.x; a3 += hi.y;
        }

        // combine the two edge-halves
        a0 += __shfl_xor(a0, 32);
        a1 += __shfl_xor(a1, 32);
        a2 += __shfl_xor(a2, 32);
        a3 += __shfl_xor(a3, 32);

        if (half == 0) {
            // self term + spills (lanes 0-31 hold the true sums)
            unsigned int ws = xw32[(size_t)node * 32 + c31];
            floatx2 lo = __builtin_amdgcn_cvt_pk_f32_fp8((int)ws, false);
            floatx2 hi = __builtin_amdgcn_cvt_pk_f32_fp8((int)ws, true);
            a0 += lo.x; a1 += lo.y; a2 += hi.x; a3 += hi.y;
            if (na > 0) {
                for (int k = 0; k < na; ++k) {
                    int2 pr = ovfA[k];
                    if (pr.x == node) {
                        unsigned int w = xw32[(size_t)pr.y * 32 + c31];
                        floatx2 l2_ = __builtin_amdgcn_cvt_pk_f32_fp8((int)w, false);
                        floatx2 h2_ = __builtin_amdgcn_cvt_pk_f32_fp8((int)w, true);
                        a0 += l2_.x; a1 += l2_.y; a2 += h2_.x; a3 += h2_.y;
                    }
                }
            }
            float h0 = a0 * dvd + bcol[0];
            float h1 = a1 * dvd + bcol[1];
            float h2 = a2 * dvd + bcol[2];
            float h3 = a3 * dvd + bcol[3];
            out[noff + col[0]] = x[noff + col[0]] + (h0 > 0.f ? h0 : 0.f);
            out[noff + col[1]] = x[noff + col[1]] + (h1 > 0.f ? h1 : 0.f);
            out[noff + col[2]] = x[noff + col[2]] + (h2 > 0.f ? h2 : 0.f);
            out[noff + col[3]] = x[noff + col[3]] + (h3 > 0.f ? h3 : 0.f);
        }
    }
}

extern "C" void kernel_launch(void* const* d_in, const int* in_sizes, int n_in,
                              void* d_out, int out_size, void* d_ws, size_t ws_size,
                              hipStream_t stream) {
    const float* x = (const float*)d_in[0];
    const int* ei = (const int*)d_in[1];
    const float* W = (const float*)d_in[2];
    const float* bias = (const float*)d_in[3];
    float* out = (float*)d_out;

    const int N = in_sizes[0] / D;   // 50000
    const int E = in_sizes[1] / 2;   // 1,600,000
    const int* src = ei;
    const int* dst = ei + E;
    const int NB = (N + BSIZE - 1) / BSIZE;  // 782 (<= NBMAX)

    // workspace (~18 MB)
    char* p = (char*)d_ws;
    int* pairs = (int*)p;            p += (size_t)NB * BCAP * sizeof(int);      // 9.6 MB
    unsigned char* xw = (unsigned char*)p; p += (size_t)N * 128;                // 6.4 MB
    int* bucket_cnt = (int*)p;       p += (size_t)NBMAX * sizeof(int);
    int* ovfA_cnt = (int*)p;         p += 16;
    int2* ovfA = (int2*)p;           p += (size_t)OVF_CAP * sizeof(int2);       // 0.5 MB
    int* ph = (int*)p;               p += (size_t)PA_BLOCKS * NB * sizeof(int); // 0.8 MB

    hipMemsetAsync(ovfA_cnt, 0, 16, stream);  // only the spill counter

    histA_kernel<<<PA_BLOCKS, 256, 0, stream>>>(dst, ph, E, NB);
    scanA_kernel<<<NB, PA_BLOCKS, 0, stream>>>(ph, bucket_cnt, NB);
    placeA_kernel<<<PA_BLOCKS, 256, 0, stream>>>(src, dst, ph, pairs,
                                                 ovfA_cnt, ovfA, E, NB);
    xw_kernel<<<NB, 256, 0, stream>>>(x, W, pairs, bucket_cnt, ovfA_cnt, ovfA, xw, N);
    gatherB_kernel<<<NB, GB_THREADS, 0, stream>>>(x, xw, pairs, bucket_cnt,
                                                  bias, ovfA_cnt, ovfA, out, N);
}